// Round 1
// baseline (342.520 us; speedup 1.0000x reference)
//
#include <hip/hip_runtime.h>
#include <stdint.h>

#define H 16
#define DH 64
#define BATCH 2
#define NSEQ 2048
#define DMODEL 1024
#define MROWS (BATCH*NSEQ)      // 4096
#define ATT_SCALE (1.0f/32.0f)  // 1/sqrt(1024)
#define LOG2E 1.44269504088896f

typedef __attribute__((ext_vector_type(8))) short short8;
typedef __attribute__((ext_vector_type(4))) float floatx4;

__device__ __forceinline__ short f2bf(float f) {
  union { float f; unsigned u; } c; c.f = f;
  unsigned u = c.u;
  unsigned r = (u + 0x7FFFu + ((u >> 16) & 1u)) >> 16;
  return (short)r;
}

// ---------------- cast x (fp32 -> bf16), vectorized ----------------
__global__ __launch_bounds__(256) void cast_x_kernel(const float* __restrict__ x,
                                                     short* __restrict__ xb, int n4) {
  int i = blockIdx.x * 256 + threadIdx.x;
  if (i < n4) {
    float4 v = ((const float4*)x)[i];
    short4 o;
    o.x = f2bf(v.x); o.y = f2bf(v.y); o.z = f2bf(v.z); o.w = f2bf(v.w);
    ((short4*)xb)[i] = o;
  }
}

// ------------- transpose + cast weight: Wt[n][k] = bf16(W[k][n]) -------------
__global__ __launch_bounds__(256) void transpose_cast(const float* __restrict__ W,
                                                      short* __restrict__ Wt) {
  __shared__ short tile[32][33];
  int k0 = blockIdx.x * 32, n0 = blockIdx.y * 32;
  int tx = threadIdx.x & 31, ty = threadIdx.x >> 5;   // ty in 0..7
#pragma unroll
  for (int i = 0; i < 4; i++) {
    int k = k0 + ty + i * 8;
    tile[tx][ty + i * 8] = f2bf(W[(size_t)k * DMODEL + n0 + tx]);
  }
  __syncthreads();
#pragma unroll
  for (int i = 0; i < 4; i++) {
    int n = n0 + ty + i * 8;
    Wt[(size_t)n * DMODEL + k0 + tx] = tile[ty + i * 8][tx];
  }
}

// ---------------- GEMM: C[M,N] = A[M,K] * Bt[N,K]^T  (bf16 in, fp32 acc) ----------------
// MODE 0: N=3072 fused QKV, bf16 out scattered to (B,H,NSEQ,DH) x {Q,K,V}
// MODE 1: N=1024, fp32 out = C + bias, row-major to d_out
template <int MODE>
__global__ __launch_bounds__(256) void gemm_bt(const short* __restrict__ A,
                                               const short* __restrict__ Bt,
                                               short* __restrict__ outb,
                                               float* __restrict__ outf,
                                               const float* __restrict__ bias,
                                               int K, int nbn) {
  __shared__ __align__(16) short As[128 * 32];
  __shared__ __align__(16) short Bs[128 * 32];
  int tid = threadIdx.x;
  int lane = tid & 63;
  int w = tid >> 6;
  int wm = w >> 1, wn = w & 1;
  int m16 = lane & 15, quad = lane >> 4;
  int bm = blockIdx.x / nbn, bn = blockIdx.x % nbn;

  floatx4 acc[4][4];
#pragma unroll
  for (int i = 0; i < 4; i++)
#pragma unroll
    for (int j = 0; j < 4; j++) acc[i][j] = (floatx4){0.f, 0.f, 0.f, 0.f};

  const short* Ablk = A + (size_t)bm * 128 * K;
  const short* Bblk = Bt + (size_t)bn * 128 * K;

  for (int k0 = 0; k0 < K; k0 += 32) {
    // stage 128x32 A and B tiles (row-major, contiguous per row)
#pragma unroll
    for (int it = 0; it < 2; ++it) {
      int idx = it * 256 + tid;       // 0..511
      int row = idx >> 2, seg = idx & 3;
      *(short8*)&As[idx * 8] = *(const short8*)(Ablk + (size_t)row * K + k0 + seg * 8);
      *(short8*)&Bs[idx * 8] = *(const short8*)(Bblk + (size_t)row * K + k0 + seg * 8);
    }
    __syncthreads();
    short8 af[4], bfr[4];
#pragma unroll
    for (int i = 0; i < 4; i++)
      af[i] = *(const short8*)&As[(wm * 64 + i * 16 + m16) * 32 + quad * 8];
#pragma unroll
    for (int j = 0; j < 4; j++)
      bfr[j] = *(const short8*)&Bs[(wn * 64 + j * 16 + m16) * 32 + quad * 8];
#pragma unroll
    for (int i = 0; i < 4; i++)
#pragma unroll
      for (int j = 0; j < 4; j++)
        acc[i][j] = __builtin_amdgcn_mfma_f32_16x16x32_bf16(af[i], bfr[j], acc[i][j], 0, 0, 0);
    __syncthreads();
  }

  // epilogue: C/D layout col=lane&15, row=quad*4+reg
#pragma unroll
  for (int i = 0; i < 4; i++) {
    int mrow_base = bm * 128 + wm * 64 + i * 16 + quad * 4;
#pragma unroll
    for (int j = 0; j < 4; j++) {
      int ncol = bn * 128 + wn * 64 + j * 16 + m16;
#pragma unroll
      for (int r = 0; r < 4; r++) {
        int grow = mrow_base + r;
        float v = acc[i][j][r];
        if (MODE == 0) {
          int b = grow >> 11, ns = grow & 2047;
          int which = ncol >> 10;           // 0=Q 1=K 2=V
          int c = ncol & 1023;
          int h = c >> 6, dh = c & 63;
          size_t oidx = (size_t)which * 4194304 +
                        (((size_t)(b * H + h) * NSEQ + ns) * DH) + dh;
          outb[oidx] = f2bf(v);
        } else {
          outf[(size_t)grow * DMODEL + ncol] = v + bias[ncol];
        }
      }
    }
  }
}

// ---------------- flash-style causal attention ----------------
// grid: (NSEQ/64, BATCH*H), block 256. Wave w owns q rows [qb*64+w*16, +16).
__global__ __launch_bounds__(256) void attn_kernel(const short* __restrict__ Qw,
                                                   const short* __restrict__ Kw,
                                                   const short* __restrict__ Vw,
                                                   short* __restrict__ ctx) {
  __shared__ __align__(16) short Ks[64 * 64];
  __shared__ __align__(16) short Vt[64 * 64];
  __shared__ __align__(16) short Ps[4][16 * 64];
  int qb = blockIdx.x;
  int bh = blockIdx.y;
  int tid = threadIdx.x, lane = tid & 63, w = tid >> 6;
  int m16 = lane & 15, quad = lane >> 4;
  const size_t base = (size_t)bh * NSEQ * DH;
  int q0 = qb * 64 + w * 16;

  // Q fragments (A-layout): lane m=lane&15 holds q-row, k contiguous
  short8 qf[2];
#pragma unroll
  for (int kk = 0; kk < 2; kk++)
    qf[kk] = *(const short8*)(Qw + base + (size_t)(q0 + m16) * DH + kk * 32 + quad * 8);

  float mrow[4], lrow[4];
  floatx4 o[4];
#pragma unroll
  for (int r = 0; r < 4; r++) { mrow[r] = -__builtin_inff(); lrow[r] = 0.f; }
#pragma unroll
  for (int d = 0; d < 4; d++) o[d] = (floatx4){0.f, 0.f, 0.f, 0.f};

  for (int kc = 0; kc <= qb; ++kc) {
    __syncthreads();  // protect Ks/Vt from previous iteration's readers
    {
      const short* Kg = Kw + base + (size_t)kc * 64 * DH;
      const short* Vg = Vw + base + (size_t)kc * 64 * DH;
      int i0 = tid * 16;
      *(short8*)&Ks[i0] = *(const short8*)(Kg + i0);
      *(short8*)&Ks[i0 + 8] = *(const short8*)(Kg + i0 + 8);
      short8 v0 = *(const short8*)(Vg + i0);
      short8 v1 = *(const short8*)(Vg + i0 + 8);
      int krow = i0 >> 6, dcol = i0 & 63;
#pragma unroll
      for (int j = 0; j < 8; j++) Vt[(dcol + j) * 64 + krow] = v0[j];
#pragma unroll
      for (int j = 0; j < 8; j++) Vt[(dcol + 8 + j) * 64 + krow] = v1[j];
    }
    __syncthreads();

    // S tile: 16 q x 64 keys per wave
    float sv[4][4];
    float mnew[4];
#pragma unroll
    for (int r = 0; r < 4; r++) mnew[r] = mrow[r];
#pragma unroll
    for (int nj = 0; nj < 4; nj++) {
      short8 kf0 = *(const short8*)&Ks[(nj * 16 + m16) * 64 + quad * 8];
      short8 kf1 = *(const short8*)&Ks[(nj * 16 + m16) * 64 + 32 + quad * 8];
      floatx4 s = (floatx4){0.f, 0.f, 0.f, 0.f};
      s = __builtin_amdgcn_mfma_f32_16x16x32_bf16(qf[0], kf0, s, 0, 0, 0);
      s = __builtin_amdgcn_mfma_f32_16x16x32_bf16(qf[1], kf1, s, 0, 0, 0);
      int key = kc * 64 + nj * 16 + m16;
#pragma unroll
      for (int r = 0; r < 4; r++) {
        int qrow = q0 + quad * 4 + r;
        float val = (key <= qrow) ? s[r] * ATT_SCALE : -__builtin_inff();
        sv[nj][r] = val;
        mnew[r] = fmaxf(mnew[r], val);
      }
    }
    float p[4][4], alpha[4];
#pragma unroll
    for (int r = 0; r < 4; r++) {
      float mx = mnew[r];
      for (int off = 1; off < 16; off <<= 1) mx = fmaxf(mx, __shfl_xor(mx, off, 16));
      mnew[r] = mx;
      alpha[r] = exp2f((mrow[r] - mx) * LOG2E);
      float sum = 0.f;
#pragma unroll
      for (int nj = 0; nj < 4; nj++) {
        float pv = exp2f((sv[nj][r] - mx) * LOG2E);
        p[nj][r] = pv;
        sum += pv;
      }
      for (int off = 1; off < 16; off <<= 1) sum += __shfl_xor(sum, off, 16);
      lrow[r] = lrow[r] * alpha[r] + sum;
      mrow[r] = mx;
    }
#pragma unroll
    for (int d = 0; d < 4; d++)
#pragma unroll
      for (int r = 0; r < 4; r++) o[d][r] *= alpha[r];

    // P: C-layout -> LDS -> A-layout (per-wave region)
    short* Pw = &Ps[w][0];
#pragma unroll
    for (int nj = 0; nj < 4; nj++)
#pragma unroll
      for (int r = 0; r < 4; r++)
        Pw[(quad * 4 + r) * 64 + nj * 16 + m16] = f2bf(p[nj][r]);
    __syncthreads();

    short8 pf[2];
#pragma unroll
    for (int kj = 0; kj < 2; kj++)
      pf[kj] = *(const short8*)&Pw[m16 * 64 + kj * 32 + quad * 8];
#pragma unroll
    for (int d = 0; d < 4; d++) {
#pragma unroll
      for (int kj = 0; kj < 2; kj++) {
        short8 vf = *(const short8*)&Vt[(d * 16 + m16) * 64 + kj * 32 + quad * 8];
        o[d] = __builtin_amdgcn_mfma_f32_16x16x32_bf16(pf[kj], vf, o[d], 0, 0, 0);
      }
    }
  }

  // epilogue: ctx in (B, NSEQ, DMODEL) bf16
  int b = bh >> 4, h = bh & 15;
#pragma unroll
  for (int r = 0; r < 4; r++) {
    int qrow = q0 + quad * 4 + r;
    float inv = 1.f / lrow[r];
#pragma unroll
    for (int d = 0; d < 4; d++) {
      size_t oidx = ((size_t)(b * NSEQ + qrow)) * DMODEL + h * DH + d * 16 + m16;
      ctx[oidx] = f2bf(o[d][r] * inv);
    }
  }
}

extern "C" void kernel_launch(void* const* d_in, const int* in_sizes, int n_in,
                              void* d_out, int out_size, void* d_ws, size_t ws_size,
                              hipStream_t stream) {
  const float* x  = (const float*)d_in[0];
  const float* Wq = (const float*)d_in[1];
  const float* Wk = (const float*)d_in[2];
  const float* Wv = (const float*)d_in[3];
  const float* Wo = (const float*)d_in[4];
  const float* bo = (const float*)d_in[5];
  float* out = (float*)d_out;

  char* ws = (char*)d_ws;
  short* xb    = (short*)(ws);                        // 8 MB  (4096x1024 bf16)
  short* wqkvt = (short*)(ws + (8ull << 20));         // 6 MB  (3 x 1024x1024 bf16, transposed)
  short* wot   = (short*)(ws + (14ull << 20));        // 2 MB
  short* qkvws = (short*)(ws + (16ull << 20));        // 24 MB (Q,K,V each (B,H,N,DH) bf16)
  short* ctx   = (short*)(ws + (40ull << 20));        // 8 MB  (B,N,D bf16)

  cast_x_kernel<<<4096, 256, 0, stream>>>(x, xb, 1048576);

  dim3 tg(32, 32);
  transpose_cast<<<tg, 256, 0, stream>>>(Wq, wqkvt);
  transpose_cast<<<tg, 256, 0, stream>>>(Wk, wqkvt + 1048576);
  transpose_cast<<<tg, 256, 0, stream>>>(Wv, wqkvt + 2097152);
  transpose_cast<<<tg, 256, 0, stream>>>(Wo, wot);

  // fused QKV projection: M=4096, N=3072, K=1024
  gemm_bt<0><<<32 * 24, 256, 0, stream>>>(xb, wqkvt, qkvws, nullptr, nullptr, 1024, 24);

  // attention
  short* qws = qkvws;
  short* kws = qkvws + 4194304;
  short* vws = qkvws + 2 * 4194304;
  dim3 ag(NSEQ / 64, BATCH * H);
  attn_kernel<<<ag, 256, 0, stream>>>(qws, kws, vws, ctx);

  // output projection + bias: M=4096, N=1024, K=1024
  gemm_bt<1><<<32 * 8, 256, 0, stream>>>(ctx, wot, nullptr, out, bo, 1024, 8);
}

// Round 2
// 239.581 us; speedup vs baseline: 1.4297x; 1.4297x over previous
//
#include <hip/hip_runtime.h>
#include <stdint.h>

#define H 16
#define DH 64
#define BATCH 2
#define NSEQ 2048
#define DMODEL 1024
#define QSZ (BATCH*H*NSEQ*DH)     // 4194304 elements per Q/K/V tensor
#define ATT_CS 0.04508422017f     // (1/sqrt(1024)) * log2(e)

typedef __attribute__((ext_vector_type(8))) short short8;
typedef __attribute__((ext_vector_type(4))) short shortx4;
typedef __attribute__((ext_vector_type(4))) float floatx4;

__device__ __forceinline__ short f2bf(float f) {
  union { float f; unsigned u; } c; c.f = f;
  unsigned u = c.u;
  unsigned r = (u + 0x7FFFu + ((u >> 16) & 1u)) >> 16;
  return (short)r;
}

// async global -> LDS, 16B per lane. lds ptr must be wave-uniform; HW adds lane*16.
__device__ __forceinline__ void gld_lds16(const short* g, short* l) {
  __builtin_amdgcn_global_load_lds((const __attribute__((address_space(1))) unsigned int*)g,
                                   (__attribute__((address_space(3))) unsigned int*)l,
                                   16, 0, 0);
}

// ---------------- cast x (fp32 -> bf16), vectorized ----------------
__global__ __launch_bounds__(256) void cast_x_kernel(const float* __restrict__ x,
                                                     short* __restrict__ xb, int n4) {
  int i = blockIdx.x * 256 + threadIdx.x;
  if (i < n4) {
    float4 v = ((const float4*)x)[i];
    short4 o;
    o.x = f2bf(v.x); o.y = f2bf(v.y); o.z = f2bf(v.z); o.w = f2bf(v.w);
    ((short4*)xb)[i] = o;
  }
}

// ------------- transpose + cast weight: Wt[n][k] = bf16(W[k][n]) -------------
__global__ __launch_bounds__(256) void transpose_cast(const float* __restrict__ W,
                                                      short* __restrict__ Wt) {
  __shared__ short tile[32][33];
  int k0 = blockIdx.x * 32, n0 = blockIdx.y * 32;
  int tx = threadIdx.x & 31, ty = threadIdx.x >> 5;
#pragma unroll
  for (int i = 0; i < 4; i++) {
    int k = k0 + ty + i * 8;
    tile[tx][ty + i * 8] = f2bf(W[(size_t)k * DMODEL + n0 + tx]);
  }
  __syncthreads();
#pragma unroll
  for (int i = 0; i < 4; i++) {
    int n = n0 + ty + i * 8;
    Wt[(size_t)n * DMODEL + k0 + tx] = tile[ty + i * 8][tx];
  }
}

// ---------------- GEMM: C[M,N] = A[M,K] * Bt[N,K]^T  (bf16 in, fp32 acc) ----------------
// MODE 0: N=3072 fused QKV. Q,K written (B,H,N,DH); V written TRANSPOSED (B,H,DH,N).
// MODE 1: N=1024, fp32 out = C + bias, row-major to d_out
template <int MODE>
__global__ __launch_bounds__(256) void gemm_bt(const short* __restrict__ A,
                                               const short* __restrict__ Bt,
                                               short* __restrict__ outb,
                                               float* __restrict__ outf,
                                               const float* __restrict__ bias,
                                               int K, int nbn) {
  __shared__ __align__(16) short As[128 * 32];
  __shared__ __align__(16) short Bs[128 * 32];
  int tid = threadIdx.x;
  int lane = tid & 63;
  int w = tid >> 6;
  int wm = w >> 1, wn = w & 1;
  int m16 = lane & 15, quad = lane >> 4;
  int bm = blockIdx.x / nbn, bn = blockIdx.x % nbn;

  floatx4 acc[4][4];
#pragma unroll
  for (int i = 0; i < 4; i++)
#pragma unroll
    for (int j = 0; j < 4; j++) acc[i][j] = (floatx4){0.f, 0.f, 0.f, 0.f};

  const short* Ablk = A + (size_t)bm * 128 * K;
  const short* Bblk = Bt + (size_t)bn * 128 * K;

  for (int k0 = 0; k0 < K; k0 += 32) {
    // async staging: wave w fills LDS shorts [w*1024, w*1024+1024)
#pragma unroll
    for (int t = 0; t < 2; t++) {
      int e = w * 1024 + t * 512 + lane * 8;   // implicit dest element for this lane
      int row = e >> 5, col = e & 31;
      gld_lds16(Ablk + (size_t)row * K + k0 + col, &As[w * 1024 + t * 512]);
      gld_lds16(Bblk + (size_t)row * K + k0 + col, &Bs[w * 1024 + t * 512]);
    }
    __syncthreads();
    short8 af[4], bfr[4];
#pragma unroll
    for (int i = 0; i < 4; i++)
      af[i] = *(const short8*)&As[(wm * 64 + i * 16 + m16) * 32 + quad * 8];
#pragma unroll
    for (int j = 0; j < 4; j++)
      bfr[j] = *(const short8*)&Bs[(wn * 64 + j * 16 + m16) * 32 + quad * 8];
#pragma unroll
    for (int i = 0; i < 4; i++)
#pragma unroll
      for (int j = 0; j < 4; j++)
        acc[i][j] = __builtin_amdgcn_mfma_f32_16x16x32_bf16(af[i], bfr[j], acc[i][j], 0, 0, 0);
    __syncthreads();
  }

  // epilogue: C/D layout col=lane&15, row=quad*4+reg
#pragma unroll
  for (int i = 0; i < 4; i++) {
    int mrow_base = bm * 128 + wm * 64 + i * 16 + quad * 4;
#pragma unroll
    for (int j = 0; j < 4; j++) {
      int ncol = bn * 128 + wn * 64 + j * 16 + m16;
      if (MODE == 0) {
        int which = ncol >> 10;
        int c = ncol & 1023;
        int h = c >> 6, dh = c & 63;
        int b = mrow_base >> 11, ns0 = mrow_base & 2047;
        if (which == 2) {
          // V transposed: (B,H,DH,NSEQ); 4 consecutive ns -> packed store
          shortx4 pk;
#pragma unroll
          for (int r = 0; r < 4; r++) pk[r] = f2bf(acc[i][j][r]);
          *(shortx4*)&outb[2 * (size_t)QSZ + (((size_t)(b * H + h) * DH + dh) * NSEQ) + ns0] = pk;
        } else {
#pragma unroll
          for (int r = 0; r < 4; r++)
            outb[(size_t)which * QSZ + (((size_t)(b * H + h) * NSEQ + ns0 + r) * DH) + dh] =
                f2bf(acc[i][j][r]);
        }
      } else {
#pragma unroll
        for (int r = 0; r < 4; r++)
          outf[(size_t)(mrow_base + r) * DMODEL + ncol] = acc[i][j][r] + bias[ncol];
      }
    }
  }
}

// ---------------- flash attention, transposed-S orientation, folded schedule ----------------
// grid (16, B*H). block i handles q-tiles qbA=i and qbB=31-i (64 rows each, 16/wave).
__global__ __launch_bounds__(256) void attn_kernel(const short* __restrict__ Qw,
                                                   const short* __restrict__ Kw,
                                                   const short* __restrict__ VtG,
                                                   short* __restrict__ ctx) {
  __shared__ __align__(16) short Ks[64 * 64];
  __shared__ __align__(16) short Vt[64 * 64];
  __shared__ __align__(16) short Ps[4][16 * 80];   // padded stride 80
  int bh = blockIdx.y;
  int tid = threadIdx.x, lane = tid & 63, w = tid >> 6;
  int m16 = lane & 15, quad = lane >> 4;
  const size_t base = (size_t)bh * NSEQ * DH;
  const short* Kg0 = Kw + base;
  const short* Vg0 = VtG + base;   // (dh, ns) block for this bh
  short* Pw = &Ps[w][0];

  int qbA = blockIdx.x;        // 0..15
  int qbB = 31 - qbA;          // 16..31
  int q0A = qbA * 64 + w * 16;
  int q0B = qbB * 64 + w * 16;

  // Q fragments (B-operand for S^T = K * Q^T): lane q=m16, k=d contiguous
  short8 qfA[2], qfB[2];
#pragma unroll
  for (int kk = 0; kk < 2; kk++) {
    qfA[kk] = *(const short8*)(Qw + base + (size_t)(q0A + m16) * DH + kk * 32 + quad * 8);
    qfB[kk] = *(const short8*)(Qw + base + (size_t)(q0B + m16) * DH + kk * 32 + quad * 8);
  }

  float mA = -__builtin_inff(), lA = 0.f, mB = -__builtin_inff(), lB = 0.f;
  floatx4 oA[4], oB[4];
#pragma unroll
  for (int d = 0; d < 4; d++) { oA[d] = (floatx4){0.f,0.f,0.f,0.f}; oB[d] = (floatx4){0.f,0.f,0.f,0.f}; }

  short8 kf[4][2], vf[4][2];

  auto do_tile = [&](int kc, int qb, int q0, const short8* qf, float& m, float& l, floatx4* o) {
    floatx4 st[4];
#pragma unroll
    for (int nj = 0; nj < 4; nj++) {
      floatx4 s = (floatx4){0.f, 0.f, 0.f, 0.f};
      s = __builtin_amdgcn_mfma_f32_16x16x32_bf16(kf[nj][0], qf[0], s, 0, 0, 0);
      s = __builtin_amdgcn_mfma_f32_16x16x32_bf16(kf[nj][1], qf[1], s, 0, 0, 0);
      st[nj] = s;
    }
    // t-domain (pre-multiplied by scale*log2e); causal mask only on diagonal chunk
    bool diag = (kc == qb);
    int qrow = q0 + m16;
    float tv[4][4];
    float mloc = -__builtin_inff();
#pragma unroll
    for (int nj = 0; nj < 4; nj++)
#pragma unroll
      for (int r = 0; r < 4; r++) {
        float v = st[nj][r] * ATT_CS;
        if (diag) {
          int key = kc * 64 + nj * 16 + quad * 4 + r;
          if (key > qrow) v = -__builtin_inff();
        }
        tv[nj][r] = v;
        mloc = fmaxf(mloc, v);
      }
    float mx = fmaxf(mloc, __shfl_xor(mloc, 16, 64));
    mx = fmaxf(mx, __shfl_xor(mx, 32, 64));
    float mnew = fmaxf(m, mx);
    float alpha = exp2f(m - mnew);
    float sum = 0.f;
#pragma unroll
    for (int nj = 0; nj < 4; nj++) {
      shortx4 pk;
#pragma unroll
      for (int r = 0; r < 4; r++) {
        float pv = exp2f(tv[nj][r] - mnew);
        sum += pv;
        pk[r] = f2bf(pv);
      }
      *(shortx4*)&Pw[m16 * 80 + nj * 16 + quad * 4] = pk;   // wave-private: no barrier
    }
    sum += __shfl_xor(sum, 16, 64);
    sum += __shfl_xor(sum, 32, 64);
    l = l * alpha + sum;
    m = mnew;
#pragma unroll
    for (int d = 0; d < 4; d++) o[d] *= alpha;
    short8 pf[2];
#pragma unroll
    for (int kj = 0; kj < 2; kj++)
      pf[kj] = *(const short8*)&Pw[m16 * 80 + kj * 32 + quad * 8];
#pragma unroll
    for (int d = 0; d < 4; d++)
#pragma unroll
      for (int kj = 0; kj < 2; kj++)
        o[d] = __builtin_amdgcn_mfma_f32_16x16x32_bf16(vf[d][kj], pf[kj], o[d], 0, 0, 0);
  };

  for (int kc = 0; kc <= qbB; ++kc) {
    __syncthreads();   // protect Ks/Vt from previous iteration's readers
    {
      const short* Kg = Kg0 + (size_t)kc * 64 * DH;   // contiguous 8KB chunk
#pragma unroll
      for (int t = 0; t < 2; t++) {
        int e = w * 1024 + t * 512 + lane * 8;
        gld_lds16(Kg + e, &Ks[w * 1024 + t * 512]);
        int dh = e >> 6, c = e & 63;
        gld_lds16(Vg0 + (size_t)dh * NSEQ + kc * 64 + c, &Vt[w * 1024 + t * 512]);
      }
    }
    __syncthreads();
    // shared fragments for both q-tiles
#pragma unroll
    for (int nj = 0; nj < 4; nj++) {
      kf[nj][0] = *(const short8*)&Ks[(nj * 16 + m16) * 64 + quad * 8];
      kf[nj][1] = *(const short8*)&Ks[(nj * 16 + m16) * 64 + 32 + quad * 8];
    }
#pragma unroll
    for (int d = 0; d < 4; d++) {
      vf[d][0] = *(const short8*)&Vt[(d * 16 + m16) * 64 + quad * 8];
      vf[d][1] = *(const short8*)&Vt[(d * 16 + m16) * 64 + 32 + quad * 8];
    }
    if (kc <= qbA) do_tile(kc, qbA, q0A, qfA, mA, lA, oA);
    do_tile(kc, qbB, q0B, qfB, mB, lB, oB);
  }

  // epilogue: O^T layout -> ctx (B, NSEQ, DMODEL) bf16; lane has q=m16, dh=d*16+quad*4+r
  int b = bh >> 4, h = bh & 15;
#pragma unroll
  for (int s = 0; s < 2; s++) {
    int q0 = s ? q0B : q0A;
    float inv = 1.f / (s ? lB : lA);
    floatx4* o = s ? oB : oA;
    size_t rowbase = ((size_t)(b * NSEQ + q0 + m16)) * DMODEL + h * DH;
#pragma unroll
    for (int d = 0; d < 4; d++) {
      shortx4 pk;
#pragma unroll
      for (int r = 0; r < 4; r++) pk[r] = f2bf(o[d][r] * inv);
      *(shortx4*)&ctx[rowbase + d * 16 + quad * 4] = pk;
    }
  }
}

extern "C" void kernel_launch(void* const* d_in, const int* in_sizes, int n_in,
                              void* d_out, int out_size, void* d_ws, size_t ws_size,
                              hipStream_t stream) {
  const float* x  = (const float*)d_in[0];
  const float* Wq = (const float*)d_in[1];
  const float* Wk = (const float*)d_in[2];
  const float* Wv = (const float*)d_in[3];
  const float* Wo = (const float*)d_in[4];
  const float* bo = (const float*)d_in[5];
  float* out = (float*)d_out;

  char* ws = (char*)d_ws;
  short* xb    = (short*)(ws);                        // 8 MB
  short* wqkvt = (short*)(ws + (8ull << 20));         // 6 MB
  short* wot   = (short*)(ws + (14ull << 20));        // 2 MB
  short* qkvws = (short*)(ws + (16ull << 20));        // 24 MB: Q,K (B,H,N,DH); V (B,H,DH,N)
  short* ctx   = (short*)(ws + (40ull << 20));        // 8 MB

  cast_x_kernel<<<4096, 256, 0, stream>>>(x, xb, 1048576);

  dim3 tg(32, 32);
  transpose_cast<<<tg, 256, 0, stream>>>(Wq, wqkvt);
  transpose_cast<<<tg, 256, 0, stream>>>(Wk, wqkvt + 1048576);
  transpose_cast<<<tg, 256, 0, stream>>>(Wv, wqkvt + 2097152);
  transpose_cast<<<tg, 256, 0, stream>>>(Wo, wot);

  // fused QKV projection: M=4096, N=3072, K=1024
  gemm_bt<0><<<32 * 24, 256, 0, stream>>>(xb, wqkvt, qkvws, nullptr, nullptr, 1024, 24);

  // attention (folded causal schedule)
  short* qws = qkvws;
  short* kws = qkvws + QSZ;
  short* vtg = qkvws + 2 * QSZ;
  dim3 ag(16, BATCH * H);
  attn_kernel<<<ag, 256, 0, stream>>>(qws, kws, vtg, ctx);

  // output projection + bias: M=4096, N=1024, K=1024
  gemm_bt<1><<<32 * 8, 256, 0, stream>>>(ctx, wot, nullptr, out, bo, 1024, 8);
}

// Round 3
// 238.969 us; speedup vs baseline: 1.4333x; 1.0026x over previous
//
#include <hip/hip_runtime.h>
#include <stdint.h>

#define H 16
#define DH 64
#define BATCH 2
#define NSEQ 2048
#define DMODEL 1024
#define QSZ (BATCH*H*NSEQ*DH)     // 4194304 elements per Q/K/V tensor
#define ATT_CS 0.04508422017f     // (1/sqrt(1024)) * log2(e)

typedef __attribute__((ext_vector_type(8))) short short8;
typedef __attribute__((ext_vector_type(4))) short shortx4;
typedef __attribute__((ext_vector_type(4))) float floatx4;

__device__ __forceinline__ short f2bf(float f) {
  union { float f; unsigned u; } c; c.f = f;
  unsigned u = c.u;
  unsigned r = (u + 0x7FFFu + ((u >> 16) & 1u)) >> 16;
  return (short)r;
}

// pack two f32 -> packed bf16x2 (round-half-up), 3 VALU ops
__device__ __forceinline__ unsigned pk2bf(float a, float b) {
  union { float f; unsigned u; } ca, cb; ca.f = a; cb.f = b;
  return __builtin_amdgcn_perm(cb.u + 0x8000u, ca.u + 0x8000u, 0x07060302u);
}

// async global -> LDS, 16B per lane. lds ptr must be wave-uniform; HW adds lane*16.
__device__ __forceinline__ void gld_lds16(const short* g, short* l) {
  __builtin_amdgcn_global_load_lds((const __attribute__((address_space(1))) unsigned int*)g,
                                   (__attribute__((address_space(3))) unsigned int*)l,
                                   16, 0, 0);
}

// ---------------- fused prep: x cast + 4 weight transposes ----------------
__global__ __launch_bounds__(256) void prep_kernel(const float* __restrict__ x,
                                                   const float* __restrict__ Wq,
                                                   const float* __restrict__ Wk,
                                                   const float* __restrict__ Wv,
                                                   const float* __restrict__ Wo,
                                                   short* __restrict__ xb,
                                                   short* __restrict__ wqkvt,
                                                   short* __restrict__ wot) {
  __shared__ short tile[32][33];
  int bid = blockIdx.x;
  if (bid < 4096) {
    int i = bid * 256 + threadIdx.x;
    float4 v = ((const float4*)x)[i];
    short4 o;
    o.x = f2bf(v.x); o.y = f2bf(v.y); o.z = f2bf(v.z); o.w = f2bf(v.w);
    ((short4*)xb)[i] = o;
  } else {
    int t = bid - 4096;
    int widx = t >> 10, rem = t & 1023;
    int bx = rem & 31, by = rem >> 5;
    const float* W = (widx == 0) ? Wq : (widx == 1) ? Wk : (widx == 2) ? Wv : Wo;
    short* dst = (widx < 3) ? (wqkvt + (size_t)widx * 1048576) : wot;
    int k0 = bx * 32, n0 = by * 32;
    int tx = threadIdx.x & 31, ty = threadIdx.x >> 5;
#pragma unroll
    for (int i = 0; i < 4; i++) {
      int k = k0 + ty + i * 8;
      tile[tx][ty + i * 8] = f2bf(W[(size_t)k * DMODEL + n0 + tx]);
    }
    __syncthreads();
#pragma unroll
    for (int i = 0; i < 4; i++) {
      int n = n0 + ty + i * 8;
      dst[(size_t)n * DMODEL + k0 + tx] = tile[ty + i * 8][tx];
    }
  }
}

// ---------------- GEMM: C[M,N] = A[M,K] * Bt[N,K]^T, double-buffered async staging --------
// MODE 0: N=3072 fused QKV. Q,K written (B,H,N,DH); V written TRANSPOSED (B,H,DH,N).
// MODE 1: N=1024, fp32 out = C + bias, row-major to d_out
template <int MODE>
__global__ __launch_bounds__(256) void gemm_bt(const short* __restrict__ A,
                                               const short* __restrict__ Bt,
                                               short* __restrict__ outb,
                                               float* __restrict__ outf,
                                               const float* __restrict__ bias,
                                               int K, int nbn) {
  __shared__ __align__(16) short As[2][4096];
  __shared__ __align__(16) short Bs[2][4096];
  int tid = threadIdx.x;
  int lane = tid & 63;
  int w = tid >> 6;
  int wm = w >> 1, wn = w & 1;
  int m16 = lane & 15, quad = lane >> 4;
  int bm = blockIdx.x / nbn, bn = blockIdx.x % nbn;

  floatx4 acc[4][4];
#pragma unroll
  for (int i = 0; i < 4; i++)
#pragma unroll
    for (int j = 0; j < 4; j++) acc[i][j] = (floatx4){0.f, 0.f, 0.f, 0.f};

  const short* Ablk = A + (size_t)bm * 128 * K;
  const short* Bblk = Bt + (size_t)bn * 128 * K;

  auto stage = [&](int k0, int b) {
#pragma unroll
    for (int t = 0; t < 2; t++) {
      int e = w * 1024 + t * 512 + lane * 8;
      int row = e >> 5, col = e & 31;
      gld_lds16(Ablk + (size_t)row * K + k0 + col, &As[b][w * 1024 + t * 512]);
      gld_lds16(Bblk + (size_t)row * K + k0 + col, &Bs[b][w * 1024 + t * 512]);
    }
  };

  stage(0, 0);
  for (int k0 = 0; k0 < K; k0 += 32) {
    int b = (k0 >> 5) & 1;
    __syncthreads();                       // drains prev stage; buf b ready
    if (k0 + 32 < K) stage(k0 + 32, b ^ 1);  // async fill of other buffer during compute
    short8 af[4], bfr[4];
#pragma unroll
    for (int i = 0; i < 4; i++)
      af[i] = *(const short8*)&As[b][(wm * 64 + i * 16 + m16) * 32 + quad * 8];
#pragma unroll
    for (int j = 0; j < 4; j++)
      bfr[j] = *(const short8*)&Bs[b][(wn * 64 + j * 16 + m16) * 32 + quad * 8];
#pragma unroll
    for (int i = 0; i < 4; i++)
#pragma unroll
      for (int j = 0; j < 4; j++)
        acc[i][j] = __builtin_amdgcn_mfma_f32_16x16x32_bf16(af[i], bfr[j], acc[i][j], 0, 0, 0);
  }

  // epilogue: C/D layout col=lane&15, row=quad*4+reg
#pragma unroll
  for (int i = 0; i < 4; i++) {
    int mrow_base = bm * 128 + wm * 64 + i * 16 + quad * 4;
#pragma unroll
    for (int j = 0; j < 4; j++) {
      int ncol = bn * 128 + wn * 64 + j * 16 + m16;
      if (MODE == 0) {
        int which = ncol >> 10;
        int c = ncol & 1023;
        int h = c >> 6, dh = c & 63;
        int b = mrow_base >> 11, ns0 = mrow_base & 2047;
        if (which == 2) {
          shortx4 pk;
#pragma unroll
          for (int r = 0; r < 4; r++) pk[r] = f2bf(acc[i][j][r]);
          *(shortx4*)&outb[2 * (size_t)QSZ + (((size_t)(b * H + h) * DH + dh) * NSEQ) + ns0] = pk;
        } else {
#pragma unroll
          for (int r = 0; r < 4; r++)
            outb[(size_t)which * QSZ + (((size_t)(b * H + h) * NSEQ + ns0 + r) * DH) + dh] =
                f2bf(acc[i][j][r]);
        }
      } else {
#pragma unroll
        for (int r = 0; r < 4; r++)
          outf[(size_t)(mrow_base + r) * DMODEL + ncol] = acc[i][j][r] + bias[ncol];
      }
    }
  }
}

// ---------------- flash attention: tr-S, folded, dbuf async staging, xor-swizzled LDS ------
// grid (16, B*H). block i handles q-tiles qbA=i and qbB=31-i (64 rows each, 16/wave).
__global__ __launch_bounds__(256) void attn_kernel(const short* __restrict__ Qw,
                                                   const short* __restrict__ Kw,
                                                   const short* __restrict__ VtG,
                                                   short* __restrict__ ctx) {
  __shared__ __align__(16) short Ks[2][4096];
  __shared__ __align__(16) short Vt[2][4096];
  __shared__ __align__(16) short Ps[2][4][16 * 72];   // [tile][wave][q*72+key]
  int bh = blockIdx.y;
  int tid = threadIdx.x, lane = tid & 63, w = tid >> 6;
  int m16 = lane & 15, quad = lane >> 4;
  int sw = m16 & 7;
  const size_t base = (size_t)bh * NSEQ * DH;
  const short* Kg0 = Kw + base;
  const short* Vg0 = VtG + base;
  short* PwA = &Ps[0][w][0];
  short* PwB = &Ps[1][w][0];

  int qbA = blockIdx.x;        // 0..15
  int qbB = 31 - qbA;          // 16..31
  int q0A = qbA * 64 + w * 16;
  int q0B = qbB * 64 + w * 16;

  short8 qfA[2], qfB[2];
#pragma unroll
  for (int kk = 0; kk < 2; kk++) {
    qfA[kk] = *(const short8*)(Qw + base + (size_t)(q0A + m16) * DH + kk * 32 + quad * 8);
    qfB[kk] = *(const short8*)(Qw + base + (size_t)(q0B + m16) * DH + kk * 32 + quad * 8);
  }

  float mA = -__builtin_inff(), lA = 0.f, mB = -__builtin_inff(), lB = 0.f;
  floatx4 oA[4], oB[4];
#pragma unroll
  for (int d = 0; d < 4; d++) { oA[d] = (floatx4){0.f,0.f,0.f,0.f}; oB[d] = (floatx4){0.f,0.f,0.f,0.f}; }

  short8 kf[4][2], vf[4][2];

  // stage chunk kc into buffer b; 16B blocks xor-swizzled: physical block pb holds
  // logical block pb ^ (row & 7)
  auto stage = [&](int kc, int b) {
#pragma unroll
    for (int t = 0; t < 2; t++) {
      int e = w * 1024 + t * 512 + lane * 8;
      int r = e >> 6;
      int g = ((e >> 3) & 7) ^ (r & 7);
      gld_lds16(Kg0 + (size_t)(kc * 64 + r) * DH + g * 8, &Ks[b][w * 1024 + t * 512]);
      gld_lds16(Vg0 + (size_t)r * NSEQ + kc * 64 + g * 8, &Vt[b][w * 1024 + t * 512]);
    }
  };

  auto tile_qk = [&](bool diag, int kc, int q0, const short8* qf,
                     float& m, float& l, float& alpha, short* Pw) {
    floatx4 st[4];
#pragma unroll
    for (int nj = 0; nj < 4; nj++) {
      floatx4 s = (floatx4){0.f, 0.f, 0.f, 0.f};
      s = __builtin_amdgcn_mfma_f32_16x16x32_bf16(kf[nj][0], qf[0], s, 0, 0, 0);
      s = __builtin_amdgcn_mfma_f32_16x16x32_bf16(kf[nj][1], qf[1], s, 0, 0, 0);
      st[nj] = s;
    }
    int qrow = q0 + m16;
    float tv[16];
    float mloc = -__builtin_inff();
#pragma unroll
    for (int nj = 0; nj < 4; nj++)
#pragma unroll
      for (int r = 0; r < 4; r++) {
        float v = st[nj][r] * ATT_CS;
        if (diag) {
          int key = kc * 64 + nj * 16 + quad * 4 + r;
          if (key > qrow) v = -__builtin_inff();
        }
        tv[nj * 4 + r] = v;
        mloc = fmaxf(mloc, v);
      }
    float mx = fmaxf(mloc, __shfl_xor(mloc, 16, 64));
    mx = fmaxf(mx, __shfl_xor(mx, 32, 64));
    float mnew = fmaxf(m, mx);
    alpha = __builtin_amdgcn_exp2f(m - mnew);
    float sum = 0.f;
#pragma unroll
    for (int nj = 0; nj < 4; nj++) {
      float p0 = __builtin_amdgcn_exp2f(tv[nj * 4 + 0] - mnew);
      float p1 = __builtin_amdgcn_exp2f(tv[nj * 4 + 1] - mnew);
      float p2 = __builtin_amdgcn_exp2f(tv[nj * 4 + 2] - mnew);
      float p3 = __builtin_amdgcn_exp2f(tv[nj * 4 + 3] - mnew);
      sum += (p0 + p1) + (p2 + p3);
      uint2 pk;
      pk.x = pk2bf(p0, p1);
      pk.y = pk2bf(p2, p3);
      *(uint2*)&Pw[m16 * 72 + nj * 16 + quad * 4] = pk;   // wave-private: no barrier
    }
    sum += __shfl_xor(sum, 16, 64);
    sum += __shfl_xor(sum, 32, 64);
    l = l * alpha + sum;
    m = mnew;
  };

  auto tile_pv = [&](float alpha, floatx4* o, const short* Pw) {
    short8 pf[2];
    pf[0] = *(const short8*)&Pw[m16 * 72 + quad * 8];
    pf[1] = *(const short8*)&Pw[m16 * 72 + 32 + quad * 8];
#pragma unroll
    for (int d = 0; d < 4; d++) {
      o[d] *= alpha;
#pragma unroll
      for (int kj = 0; kj < 2; kj++)
        o[d] = __builtin_amdgcn_mfma_f32_16x16x32_bf16(vf[d][kj], pf[kj], o[d], 0, 0, 0);
    }
  };

  stage(0, 0);
  for (int kc = 0; kc <= qbB; ++kc) {
    int b = kc & 1;
    __syncthreads();                          // prev stage drained: buf b ready
    if (kc < qbB) stage(kc + 1, b ^ 1);       // overlap next chunk's loads with compute
#pragma unroll
    for (int nj = 0; nj < 4; nj++) {
      kf[nj][0] = *(const short8*)&Ks[b][(nj * 16 + m16) * 64 + ((quad ^ sw) * 8)];
      kf[nj][1] = *(const short8*)&Ks[b][(nj * 16 + m16) * 64 + (((4 + quad) ^ sw) * 8)];
    }
#pragma unroll
    for (int d = 0; d < 4; d++) {
      vf[d][0] = *(const short8*)&Vt[b][(d * 16 + m16) * 64 + ((quad ^ sw) * 8)];
      vf[d][1] = *(const short8*)&Vt[b][(d * 16 + m16) * 64 + (((4 + quad) ^ sw) * 8)];
    }
    if (kc <= qbA) {
      float aA, aB;
      tile_qk(kc == qbA, kc, q0A, qfA, mA, lA, aA, PwA);
      tile_qk(false,     kc, q0B, qfB, mB, lB, aB, PwB);
      tile_pv(aA, oA, PwA);
      tile_pv(aB, oB, PwB);
    } else {
      float aB;
      tile_qk(kc == qbB, kc, q0B, qfB, mB, lB, aB, PwB);
      tile_pv(aB, oB, PwB);
    }
  }

  // epilogue: O^T layout -> ctx (B, NSEQ, DMODEL) bf16; lane has q=m16, dh=d*16+quad*4+r
  int b = bh >> 4, h = bh & 15;
#pragma unroll
  for (int s = 0; s < 2; s++) {
    int q0 = s ? q0B : q0A;
    float inv = 1.f / (s ? lB : lA);
    floatx4* o = s ? oB : oA;
    size_t rowbase = ((size_t)(b * NSEQ + q0 + m16)) * DMODEL + h * DH;
#pragma unroll
    for (int d = 0; d < 4; d++) {
      shortx4 pk;
#pragma unroll
      for (int r = 0; r < 4; r++) pk[r] = f2bf(o[d][r] * inv);
      *(shortx4*)&ctx[rowbase + d * 16 + quad * 4] = pk;
    }
  }
}

extern "C" void kernel_launch(void* const* d_in, const int* in_sizes, int n_in,
                              void* d_out, int out_size, void* d_ws, size_t ws_size,
                              hipStream_t stream) {
  const float* x  = (const float*)d_in[0];
  const float* Wq = (const float*)d_in[1];
  const float* Wk = (const float*)d_in[2];
  const float* Wv = (const float*)d_in[3];
  const float* Wo = (const float*)d_in[4];
  const float* bo = (const float*)d_in[5];
  float* out = (float*)d_out;

  char* ws = (char*)d_ws;
  short* xb    = (short*)(ws);                        // 8 MB
  short* wqkvt = (short*)(ws + (8ull << 20));         // 6 MB
  short* wot   = (short*)(ws + (14ull << 20));        // 2 MB
  short* qkvws = (short*)(ws + (16ull << 20));        // 24 MB: Q,K (B,H,N,DH); V (B,H,DH,N)
  short* ctx   = (short*)(ws + (40ull << 20));        // 8 MB

  prep_kernel<<<8192, 256, 0, stream>>>(x, Wq, Wk, Wv, Wo, xb, wqkvt, wot);

  // fused QKV projection: M=4096, N=3072, K=1024
  gemm_bt<0><<<32 * 24, 256, 0, stream>>>(xb, wqkvt, qkvws, nullptr, nullptr, 1024, 24);

  // attention (folded causal schedule)
  short* qws = qkvws;
  short* kws = qkvws + QSZ;
  short* vtg = qkvws + 2 * QSZ;
  dim3 ag(16, BATCH * H);
  attn_kernel<<<ag, 256, 0, stream>>>(qws, kws, vtg, ctx);

  // output projection + bias: M=4096, N=1024, K=1024
  gemm_bt<1><<<32 * 8, 256, 0, stream>>>(ctx, wot, nullptr, out, bo, 1024, 8);
}

// Round 5
// 201.682 us; speedup vs baseline: 1.6983x; 1.1849x over previous
//
#include <hip/hip_runtime.h>
#include <stdint.h>

#define H 16
#define DH 64
#define BATCH 2
#define NSEQ 2048
#define DMODEL 1024
#define QSZ (BATCH*H*NSEQ*DH)     // 4194304 elements per Q/K/V tensor
#define ATT_CS 0.04508422017f     // (1/sqrt(1024)) * log2(e), pre-applied to Q

typedef __attribute__((ext_vector_type(8))) short short8;
typedef __attribute__((ext_vector_type(4))) short shortx4;
typedef __attribute__((ext_vector_type(4))) float floatx4;

__device__ __forceinline__ short f2bf(float f) {
  union { float f; unsigned u; } c; c.f = f;
  unsigned u = c.u;
  unsigned r = (u + 0x7FFFu + ((u >> 16) & 1u)) >> 16;
  return (short)r;
}

// pack two f32 -> packed bf16x2 (round-half-up), 3 VALU ops
__device__ __forceinline__ unsigned pk2bf(float a, float b) {
  union { float f; unsigned u; } ca, cb; ca.f = a; cb.f = b;
  return __builtin_amdgcn_perm(cb.u + 0x8000u, ca.u + 0x8000u, 0x07060302u);
}

// async global -> LDS, 16B per lane. lds ptr must be wave-uniform; HW adds lane*16.
__device__ __forceinline__ void gld_lds16(const short* g, short* l) {
  __builtin_amdgcn_global_load_lds((const __attribute__((address_space(1))) unsigned int*)g,
                                   (__attribute__((address_space(3))) unsigned int*)l,
                                   16, 0, 0);
}

// ---------------- fused prep: x cast + 4 weight transposes ----------------
__global__ __launch_bounds__(256) void prep_kernel(const float* __restrict__ x,
                                                   const float* __restrict__ Wq,
                                                   const float* __restrict__ Wk,
                                                   const float* __restrict__ Wv,
                                                   const float* __restrict__ Wo,
                                                   short* __restrict__ xb,
                                                   short* __restrict__ wqkvt,
                                                   short* __restrict__ wot) {
  __shared__ short tile[32][33];
  int bid = blockIdx.x;
  if (bid < 4096) {
    int i = bid * 256 + threadIdx.x;
    float4 v = ((const float4*)x)[i];
    short4 o;
    o.x = f2bf(v.x); o.y = f2bf(v.y); o.z = f2bf(v.z); o.w = f2bf(v.w);
    ((short4*)xb)[i] = o;
  } else {
    int t = bid - 4096;
    int widx = t >> 10, rem = t & 1023;
    int bx = rem & 31, by = rem >> 5;
    const float* W = (widx == 0) ? Wq : (widx == 1) ? Wk : (widx == 2) ? Wv : Wo;
    short* dst = (widx < 3) ? (wqkvt + (size_t)widx * 1048576) : wot;
    int k0 = bx * 32, n0 = by * 32;
    int tx = threadIdx.x & 31, ty = threadIdx.x >> 5;
#pragma unroll
    for (int i = 0; i < 4; i++) {
      int k = k0 + ty + i * 8;
      tile[tx][ty + i * 8] = f2bf(W[(size_t)k * DMODEL + n0 + tx]);
    }
    __syncthreads();
#pragma unroll
    for (int i = 0; i < 4; i++) {
      int n = n0 + ty + i * 8;
      dst[(size_t)n * DMODEL + k0 + tx] = tile[ty + i * 8][tx];
    }
  }
}

// ---------------- GEMM: C[M,N] = A[M,K] * Bt[N,K]^T, double-buffered async staging --------
// MODE 0: N=3072 fused QKV. Q (pre-scaled by ATT_CS), K written (B,H,N,DH);
//         V written TRANSPOSED (B,H,DH,N).
// MODE 1: N=1024, fp32 out = C + bias, row-major to d_out
template <int MODE>
__global__ __launch_bounds__(256) void gemm_bt(const short* __restrict__ A,
                                               const short* __restrict__ Bt,
                                               short* __restrict__ outb,
                                               float* __restrict__ outf,
                                               const float* __restrict__ bias,
                                               int K, int nbn) {
  __shared__ __align__(16) short As[2][4096];
  __shared__ __align__(16) short Bs[2][4096];
  int tid = threadIdx.x;
  int lane = tid & 63;
  int w = tid >> 6;
  int wm = w >> 1, wn = w & 1;
  int m16 = lane & 15, quad = lane >> 4;
  int bm = blockIdx.x / nbn, bn = blockIdx.x % nbn;

  floatx4 acc[4][4];
#pragma unroll
  for (int i = 0; i < 4; i++)
#pragma unroll
    for (int j = 0; j < 4; j++) acc[i][j] = (floatx4){0.f, 0.f, 0.f, 0.f};

  const short* Ablk = A + (size_t)bm * 128 * K;
  const short* Bblk = Bt + (size_t)bn * 128 * K;

  auto stage = [&](int k0, int b) {
#pragma unroll
    for (int t = 0; t < 2; t++) {
      int e = w * 1024 + t * 512 + lane * 8;
      int row = e >> 5, col = e & 31;
      gld_lds16(Ablk + (size_t)row * K + k0 + col, &As[b][w * 1024 + t * 512]);
      gld_lds16(Bblk + (size_t)row * K + k0 + col, &Bs[b][w * 1024 + t * 512]);
    }
  };

  stage(0, 0);
  for (int k0 = 0; k0 < K; k0 += 32) {
    int b = (k0 >> 5) & 1;
    __syncthreads();                       // drains prev stage; buf b ready
    if (k0 + 32 < K) stage(k0 + 32, b ^ 1);  // async fill of other buffer during compute
    short8 af[4], bfr[4];
#pragma unroll
    for (int i = 0; i < 4; i++)
      af[i] = *(const short8*)&As[b][(wm * 64 + i * 16 + m16) * 32 + quad * 8];
#pragma unroll
    for (int j = 0; j < 4; j++)
      bfr[j] = *(const short8*)&Bs[b][(wn * 64 + j * 16 + m16) * 32 + quad * 8];
#pragma unroll
    for (int i = 0; i < 4; i++)
#pragma unroll
      for (int j = 0; j < 4; j++)
        acc[i][j] = __builtin_amdgcn_mfma_f32_16x16x32_bf16(af[i], bfr[j], acc[i][j], 0, 0, 0);
  }

  // epilogue: C/D layout col=lane&15, row=quad*4+reg
#pragma unroll
  for (int i = 0; i < 4; i++) {
    int mrow_base = bm * 128 + wm * 64 + i * 16 + quad * 4;
#pragma unroll
    for (int j = 0; j < 4; j++) {
      int ncol = bn * 128 + wn * 64 + j * 16 + m16;
      if (MODE == 0) {
        int which = ncol >> 10;
        int c = ncol & 1023;
        int h = c >> 6, dh = c & 63;
        int b = mrow_base >> 11, ns0 = mrow_base & 2047;
        if (which == 2) {
          shortx4 pk;
#pragma unroll
          for (int r = 0; r < 4; r++) pk[r] = f2bf(acc[i][j][r]);
          *(shortx4*)&outb[2 * (size_t)QSZ + (((size_t)(b * H + h) * DH + dh) * NSEQ) + ns0] = pk;
        } else {
          float sc = (which == 0) ? ATT_CS : 1.0f;   // pre-scale Q for attention
#pragma unroll
          for (int r = 0; r < 4; r++)
            outb[(size_t)which * QSZ + (((size_t)(b * H + h) * NSEQ + ns0 + r) * DH) + dh] =
                f2bf(acc[i][j][r] * sc);
        }
      } else {
#pragma unroll
        for (int r = 0; r < 4; r++)
          outf[(size_t)(mrow_base + r) * DMODEL + ncol] = acc[i][j][r] + bias[ncol];
      }
    }
  }
}

// ---------------- flash attention: tr-S, folded, single-buffer staging, swizzled LDS ------
// grid (16, B*H). block i handles q-tiles qbA=i and qbB=31-i (64 rows each, 16/wave).
__global__ __launch_bounds__(256) void attn_kernel(const short* __restrict__ Qw,
                                                   const short* __restrict__ Kw,
                                                   const short* __restrict__ VtG,
                                                   short* __restrict__ ctx) {
  __shared__ __align__(16) short Ks[4096];
  __shared__ __align__(16) short Vt[4096];
  __shared__ __align__(16) short Ps[2][4][16 * 72];   // [tile][wave][q*72+key]
  int bh = blockIdx.y;
  int tid = threadIdx.x, lane = tid & 63, w = tid >> 6;
  int m16 = lane & 15, quad = lane >> 4;
  int sw = m16 & 7;
  const size_t base = (size_t)bh * NSEQ * DH;
  const short* Kg0 = Kw + base;
  const short* Vg0 = VtG + base;
  short* PwA = &Ps[0][w][0];
  short* PwB = &Ps[1][w][0];

  int qbA = blockIdx.x;        // 0..15
  int qbB = 31 - qbA;          // 16..31
  int q0A = qbA * 64 + w * 16;
  int q0B = qbB * 64 + w * 16;

  short8 qfA[2], qfB[2];
#pragma unroll
  for (int kk = 0; kk < 2; kk++) {
    qfA[kk] = *(const short8*)(Qw + base + (size_t)(q0A + m16) * DH + kk * 32 + quad * 8);
    qfB[kk] = *(const short8*)(Qw + base + (size_t)(q0B + m16) * DH + kk * 32 + quad * 8);
  }

  float mA = -__builtin_inff(), lA = 0.f, mB = -__builtin_inff(), lB = 0.f;
  floatx4 oA[4], oB[4];
#pragma unroll
  for (int d = 0; d < 4; d++) { oA[d] = (floatx4){0.f,0.f,0.f,0.f}; oB[d] = (floatx4){0.f,0.f,0.f,0.f}; }

  short8 kf[4][2], vf[4][2];

  // stage chunk kc; 16B blocks xor-swizzled: physical block g holds logical g ^ (row & 7)
  auto stage = [&](int kc) {
#pragma unroll
    for (int t = 0; t < 2; t++) {
      int e = w * 1024 + t * 512 + lane * 8;
      int r = e >> 6;
      int g = ((e >> 3) & 7) ^ (r & 7);
      gld_lds16(Kg0 + (size_t)(kc * 64 + r) * DH + g * 8, &Ks[w * 1024 + t * 512]);
      gld_lds16(Vg0 + (size_t)r * NSEQ + kc * 64 + g * 8, &Vt[w * 1024 + t * 512]);
    }
  };

  auto tile_qk = [&](bool diag, int kc, int q0, const short8* qf,
                     float& m, float& l, float& alpha, short* Pw) {
    floatx4 st[4];
#pragma unroll
    for (int nj = 0; nj < 4; nj++) {
      floatx4 s = (floatx4){0.f, 0.f, 0.f, 0.f};
      s = __builtin_amdgcn_mfma_f32_16x16x32_bf16(kf[nj][0], qf[0], s, 0, 0, 0);
      s = __builtin_amdgcn_mfma_f32_16x16x32_bf16(kf[nj][1], qf[1], s, 0, 0, 0);
      st[nj] = s;
    }
    int qrow = q0 + m16;
    float tv[16];
    float mloc = -__builtin_inff();
#pragma unroll
    for (int nj = 0; nj < 4; nj++)
#pragma unroll
      for (int r = 0; r < 4; r++) {
        float v = st[nj][r];                 // Q pre-scaled: already in log2 domain
        if (diag) {
          int key = kc * 64 + nj * 16 + quad * 4 + r;
          if (key > qrow) v = -__builtin_inff();
        }
        tv[nj * 4 + r] = v;
        mloc = fmaxf(mloc, v);
      }
    float mx = fmaxf(mloc, __shfl_xor(mloc, 16, 64));
    mx = fmaxf(mx, __shfl_xor(mx, 32, 64));
    float mnew = fmaxf(m, mx);
    alpha = __builtin_amdgcn_exp2f(m - mnew);
    float sum = 0.f;
#pragma unroll
    for (int nj = 0; nj < 4; nj++) {
      float p0 = __builtin_amdgcn_exp2f(tv[nj * 4 + 0] - mnew);
      float p1 = __builtin_amdgcn_exp2f(tv[nj * 4 + 1] - mnew);
      float p2 = __builtin_amdgcn_exp2f(tv[nj * 4 + 2] - mnew);
      float p3 = __builtin_amdgcn_exp2f(tv[nj * 4 + 3] - mnew);
      sum += (p0 + p1) + (p2 + p3);
      uint2 pk;
      pk.x = pk2bf(p0, p1);
      pk.y = pk2bf(p2, p3);
      *(uint2*)&Pw[m16 * 72 + nj * 16 + quad * 4] = pk;   // wave-private: no barrier
    }
    sum += __shfl_xor(sum, 16, 64);
    sum += __shfl_xor(sum, 32, 64);
    l = l * alpha + sum;
    m = mnew;
  };

  auto tile_pv = [&](float alpha, floatx4* o, const short* Pw) {
    short8 pf[2];
    pf[0] = *(const short8*)&Pw[m16 * 72 + quad * 8];
    pf[1] = *(const short8*)&Pw[m16 * 72 + 32 + quad * 8];
#pragma unroll
    for (int d = 0; d < 4; d++) {
      o[d] *= alpha;
#pragma unroll
      for (int kj = 0; kj < 2; kj++)
        o[d] = __builtin_amdgcn_mfma_f32_16x16x32_bf16(vf[d][kj], pf[kj], o[d], 0, 0, 0);
    }
  };

  for (int kc = 0; kc <= qbB; ++kc) {
    __syncthreads();     // all waves done reading previous chunk
    stage(kc);           // async issue
    __syncthreads();     // vmcnt(0) drain at barrier: chunk staged
#pragma unroll
    for (int nj = 0; nj < 4; nj++) {
      kf[nj][0] = *(const short8*)&Ks[(nj * 16 + m16) * 64 + ((quad ^ sw) * 8)];
      kf[nj][1] = *(const short8*)&Ks[(nj * 16 + m16) * 64 + (((4 + quad) ^ sw) * 8)];
    }
#pragma unroll
    for (int d = 0; d < 4; d++) {
      vf[d][0] = *(const short8*)&Vt[(d * 16 + m16) * 64 + ((quad ^ sw) * 8)];
      vf[d][1] = *(const short8*)&Vt[(d * 16 + m16) * 64 + (((4 + quad) ^ sw) * 8)];
    }
    if (kc <= qbA) {
      float aA, aB;
      tile_qk(kc == qbA, kc, q0A, qfA, mA, lA, aA, PwA);
      tile_qk(false,     kc, q0B, qfB, mB, lB, aB, PwB);
      tile_pv(aA, oA, PwA);
      tile_pv(aB, oB, PwB);
    } else {
      float aB;
      tile_qk(kc == qbB, kc, q0B, qfB, mB, lB, aB, PwB);
      tile_pv(aB, oB, PwB);
    }
  }

  // epilogue: O^T layout -> ctx (B, NSEQ, DMODEL) bf16; lane has q=m16, dh=d*16+quad*4+r
  int b = bh >> 4, h = bh & 15;
#pragma unroll
  for (int s = 0; s < 2; s++) {
    int q0 = s ? q0B : q0A;
    float inv = 1.f / (s ? lB : lA);
    floatx4* o = s ? oB : oA;
    size_t rowbase = ((size_t)(b * NSEQ + q0 + m16)) * DMODEL + h * DH;
#pragma unroll
    for (int d = 0; d < 4; d++) {
      shortx4 pk;
#pragma unroll
      for (int r = 0; r < 4; r++) pk[r] = f2bf(o[d][r] * inv);
      *(shortx4*)&ctx[rowbase + d * 16 + quad * 4] = pk;
    }
  }
}

extern "C" void kernel_launch(void* const* d_in, const int* in_sizes, int n_in,
                              void* d_out, int out_size, void* d_ws, size_t ws_size,
                              hipStream_t stream) {
  const float* x  = (const float*)d_in[0];
  const float* Wq = (const float*)d_in[1];
  const float* Wk = (const float*)d_in[2];
  const float* Wv = (const float*)d_in[3];
  const float* Wo = (const float*)d_in[4];
  const float* bo = (const float*)d_in[5];
  float* out = (float*)d_out;

  char* ws = (char*)d_ws;
  short* xb    = (short*)(ws);                        // 8 MB
  short* wqkvt = (short*)(ws + (8ull << 20));         // 6 MB
  short* wot   = (short*)(ws + (14ull << 20));        // 2 MB
  short* qkvws = (short*)(ws + (16ull << 20));        // 24 MB: Q,K (B,H,N,DH); V (B,H,DH,N)
  short* ctx   = (short*)(ws + (40ull << 20));        // 8 MB

  prep_kernel<<<8192, 256, 0, stream>>>(x, Wq, Wk, Wv, Wo, xb, wqkvt, wot);

  // fused QKV projection: M=4096, N=3072, K=1024
  gemm_bt<0><<<32 * 24, 256, 0, stream>>>(xb, wqkvt, qkvws, nullptr, nullptr, 1024, 24);

  // attention (folded causal schedule)
  short* qws = qkvws;
  short* kws = qkvws + QSZ;
  short* vtg = qkvws + 2 * QSZ;
  dim3 ag(16, BATCH * H);
  attn_kernel<<<ag, 256, 0, stream>>>(qws, kws, vtg, ctx);

  // output projection + bias: M=4096, N=1024, K=1024
  gemm_bt<1><<<32 * 8, 256, 0, stream>>>(ctx, wot, nullptr, out, bo, 1024, 8);
}